// Round 15
// baseline (2609.136 us; speedup 1.0000x reference)
//
#include <hip/hip_runtime.h>
#include <math.h>

// ---------------- problem constants ----------------
#define NTOT 16384
#define NTT  8192
#define NCC  8192
#define DIM  128
#define AB   6.103515625e-05f        // p/NT = 0.5/8192 (exact)
#define LOG2E 1.4426950408889634f
#define QLO  6.0f                    // u8 quantization range for M: [6,24]
#define QSTEP (18.0f/255.0f)
#define QSCALE (255.0f/18.0f)
#define NWG  512u                    // k_sink grid: 16 x 32; 2/CU guaranteed co-resident

#define EXP2R(x) __builtin_amdgcn_exp2f(x)
#define SQRTR(x) __builtin_amdgcn_sqrtf(x)

// ---------------- scal slots ----------------
#define S_C2    2
#define S_KS    3
#define S_DELTA 4
#define S_E     5
#define S_V     6
#define S_U(t) (8 + (t))             // U^t, t=0..10
#define S_W(t) (24 + (t))            // W^t, t=1..10
#define S_SYNC  48                   // u32 cnt @48, u32 gen @49

// ---------------- ws layout (bytes) ----------------
#define N_SLABS 27
#define OFF_SCAL 0                               // f32[256]
#define OFF_ACC  1024
#define OFF_RN   (OFF_ACC + N_SLABS*NCC*4)       // f32[16384]
#define OFF_XH   (OFF_RN + NTOT*4)               // bf16 hi fragments (4 MB)
#define OFF_XL   (OFF_XH + NTOT*DIM*2)           // bf16 lo fragments (4 MB)
#define OFF_M    (OFF_XL + NTOT*DIM*2)           // u8 M [8192*8192] (67 MB)

typedef short bf16x8 __attribute__((ext_vector_type(8)));
typedef float f32x4  __attribute__((ext_vector_type(4)));

__device__ __forceinline__ float aload(const float* p){
  return __hip_atomic_load(p, __ATOMIC_RELAXED, __HIP_MEMORY_SCOPE_AGENT);
}
__device__ __forceinline__ void cvt4(unsigned v, float* f){
  f[0] = (float)(v & 0xFFu);
  f[1] = (float)((v >> 8) & 0xFFu);
  f[2] = (float)((v >> 16) & 0xFFu);
  f[3] = (float)(v >> 24);
}

// sense-reversing software grid barrier (R1-validated coherence pattern)
__device__ __forceinline__ void gbar(unsigned* sync, int tid){
  __syncthreads();                       // drains all this-WG memory ops (vmcnt(0) before s_barrier)
  if (tid==0){
    unsigned g = __hip_atomic_load(&sync[1], __ATOMIC_RELAXED, __HIP_MEMORY_SCOPE_AGENT);
    __threadfence();
    unsigned old = __hip_atomic_fetch_add(&sync[0], 1u, __ATOMIC_ACQ_REL, __HIP_MEMORY_SCOPE_AGENT);
    if (old == NWG-1u){
      __hip_atomic_store(&sync[0], 0u, __ATOMIC_RELAXED, __HIP_MEMORY_SCOPE_AGENT);
      __hip_atomic_fetch_add(&sync[1], 1u, __ATOMIC_RELEASE, __HIP_MEMORY_SCOPE_AGENT);
    } else {
      while (__hip_atomic_load(&sync[1], __ATOMIC_ACQUIRE, __HIP_MEMORY_SCOPE_AGENT) == g)
        __builtin_amdgcn_s_sleep(8);
    }
    __threadfence();
  }
  __syncthreads();
}

// ---------------- pack: X fp32 -> bf16 hi/lo MFMA-fragment layout + row norms ----------------
__global__ __launch_bounds__(256) void k_pack(const float* __restrict__ X,
                                              short* __restrict__ Xh, short* __restrict__ Xl,
                                              float* __restrict__ rn){
  int tid = threadIdx.x;
  int m = tid >> 4, c = tid & 15;
  int tile = blockIdx.x;
  int row = tile*16 + m;
  const float* src = X + (size_t)row*DIM + c*8;
  float4 f0 = *reinterpret_cast<const float4*>(src);
  float4 f1 = *reinterpret_cast<const float4*>(src + 4);
  float f[8] = {f0.x,f0.y,f0.z,f0.w,f1.x,f1.y,f1.z,f1.w};
  float ss = 0.f;
  #pragma unroll
  for (int i=0;i<8;i++) ss += f[i]*f[i];
  #pragma unroll
  for (int off=1; off<16; off<<=1) ss += __shfl_xor(ss, off);
  if (c==0) rn[row] = ss;
  bf16x8 h, l;
  #pragma unroll
  for (int i=0;i<8;i++){
    unsigned u  = __float_as_uint(f[i]);
    unsigned rh = (u + 0x7FFFu + ((u>>16)&1u)) & 0xFFFF0000u;
    h[i] = (short)(rh>>16);
    float fl = f[i] - __uint_as_float(rh);
    unsigned u2 = __float_as_uint(fl);
    l[i] = (short)((u2 + 0x7FFFu + ((u2>>16)&1u)) >> 16);
  }
  int ks = c >> 2, q = c & 3;
  size_t addr = ((size_t)((tile*4 + ks)*64) + m + 16*q)*8;
  *reinterpret_cast<bf16x8*>(Xh + addr) = h;
  *reinterpret_cast<bf16x8*>(Xl + addr) = l;
}

// ---------------- gemm: hi/lo MFMA; M=sqrt(clip); u8-quantized store; fp32 sum/max partials ----------------
__global__ __launch_bounds__(256) void k_gemm(const short* __restrict__ Xh, const short* __restrict__ Xl,
                                              unsigned char* __restrict__ Mq,
                                              const float* __restrict__ rn, float* __restrict__ gp){
  __shared__ __align__(16) unsigned char tile[64*80];
  __shared__ float ssum[4], smax[4];
  int tid=threadIdx.x, wave=tid>>6, lane=tid&63;
  int l15=lane&15, quad=lane>>4;
  int rowA = blockIdx.y*64 + (wave>>1)*32;
  int colC = blockIdx.x*64 + (wave&1)*32;
  int tA = rowA >> 4;
  int tB = (NTT + colC) >> 4;
  f32x4 acc[2][2] = {};
  #pragma unroll
  for (int ks=0; ks<4; ks++){
    bf16x8 Ah[2], Al[2], Bh[2], Bl[2];
    #pragma unroll
    for (int t=0;t<2;t++){
      size_t aA = ((size_t)(((tA+t)*4+ks)*64) + lane)*8;
      size_t aB = ((size_t)(((tB+t)*4+ks)*64) + lane)*8;
      Ah[t] = *reinterpret_cast<const bf16x8*>(Xh + aA);
      Al[t] = *reinterpret_cast<const bf16x8*>(Xl + aA);
      Bh[t] = *reinterpret_cast<const bf16x8*>(Xh + aB);
      Bl[t] = *reinterpret_cast<const bf16x8*>(Xl + aB);
    }
    #pragma unroll
    for (int ti=0;ti<2;ti++)
      #pragma unroll
      for (int tj=0;tj<2;tj++){
        acc[ti][tj] = __builtin_amdgcn_mfma_f32_16x16x32_bf16(Ah[ti], Bh[tj], acc[ti][tj],0,0,0);
        acc[ti][tj] = __builtin_amdgcn_mfma_f32_16x16x32_bf16(Ah[ti], Bl[tj], acc[ti][tj],0,0,0);
        acc[ti][tj] = __builtin_amdgcn_mfma_f32_16x16x32_bf16(Al[ti], Bh[tj], acc[ti][tj],0,0,0);
      }
  }
  float lsum = 0.f, lmax = 0.f;
  #pragma unroll
  for (int ti=0;ti<2;ti++)
    #pragma unroll
    for (int tj=0;tj<2;tj++)
      #pragma unroll
      for (int r=0;r<4;r++){
        int lr = (wave>>1)*32 + ti*16 + quad*4 + r;
        int lc = (wave&1)*32 + tj*16 + l15;
        int gr = blockIdx.y*64 + lr;
        int gc = blockIdx.x*64 + lc;
        float g  = acc[ti][tj][r];
        float d2 = fmaxf(rn[gr] - 2.f*g + rn[NTT+gc], 1e-10f);
        float m  = SQRTR(d2);
        int q = (int)fmaf(m, QSCALE, -QLO*QSCALE + 0.5f);
        q = min(max(q, 0), 255);
        tile[lr*80 + lc] = (unsigned char)q;
        lsum += m; lmax = fmaxf(lmax, m);
      }
  #pragma unroll
  for (int off=32; off; off>>=1){
    lsum += __shfl_xor(lsum, off);
    lmax  = fmaxf(lmax, __shfl_xor(lmax, off));
  }
  if (lane==0){ ssum[wave]=lsum; smax[wave]=lmax; }
  __syncthreads();
  if (tid==0){
    int wg = blockIdx.y*128 + blockIdx.x;
    gp[wg]         = ssum[0]+ssum[1]+ssum[2]+ssum[3];
    gp[16384 + wg] = fmaxf(fmaxf(smax[0],smax[1]), fmaxf(smax[2],smax[3]));
  }
  int lr = tid>>2, s16 = tid&3;
  uint4 v = *reinterpret_cast<const uint4*>(&tile[lr*80 + s16*16]);
  *reinterpret_cast<uint4*>(Mq + (size_t)(blockIdx.y*64+lr)*NCC + blockIdx.x*64 + s16*16) = v;
}

// ---------------- fused Sinkhorn: scal + 21 passes + finalize, ONE kernel, software grid barrier ----------------
__global__ __launch_bounds__(256,2) void k_sink(const unsigned char* __restrict__ Mq,
      float* __restrict__ accs, float* scal, const float* __restrict__ gp,
      float* __restrict__ out){
  __shared__ float red[4][512];
  unsigned* sync = (unsigned*)scal + S_SYNC;
  int tid=threadIdx.x, wave=tid>>6, lane=tid&63;
  int wg = blockIdx.x;
  int bx = wg & 15, by = wg >> 4;             // 16 x 32
  int jbase = bx*512, rowbase = by*256 + wave*64;

  // ---- scal phase (WG0 only) ----
  if (wg==0){
    __shared__ float sr[4], mr[4];
    float s=0.f, mx=0.f;
    for (int i=tid;i<16384;i+=256){ s+=gp[i]; mx=fmaxf(mx,gp[16384+i]); }
    #pragma unroll
    for (int off=1; off<64; off<<=1){ s+=__shfl_xor(s,off); mx=fmaxf(mx,__shfl_xor(mx,off)); }
    if (lane==0){ sr[wave]=s; mr[wave]=mx; }
    __syncthreads();
    if (tid==0){
      float Msum=sr[0]+sr[1]+sr[2]+sr[3];
      float delta=fmaxf(fmaxf(mr[0],mr[1]),fmaxf(mr[2],mr[3]));
      float c2=-(671088640.0f/Msum)*LOG2E;
      scal[S_C2]=c2; scal[S_KS]=EXP2R(c2*delta)+1e-6f; scal[S_DELTA]=delta;
    }
  }
  gbar(sync, tid);
  float c2 = aload(&scal[S_C2]), Ks = aload(&scal[S_KS]);
  float cs = c2*QSTEP, cb = c2*QLO;

  float usl = 0.5f, wsl = 0.f, Wl = 0.f;      // after iter k: us^k, ws^k, W^k
  const unsigned char* mp = Mq + (size_t)rowbase*NCC + jbase + lane*8;

  #pragma unroll 1
  for (int k=1; k<=10; ++k){
    float* tacc = accs + (size_t)(k-1)*NCC;
    float* sacc = accs + (size_t)(10+k)*NCC;
    const float* saccPrev = accs + (size_t)(10+k-1)*NCC;
    // ---- phase A: tacc_j += sum_i e_ij * u^{k-1}_i ; bx==0 accumulates U^{k-1} ----
    float uv;
    if (k==1) uv = AB;
    else      uv = AB/(aload(&saccPrev[rowbase + lane]) + 1e-6f*Wl + Ks*wsl);
    if (bx==0){
      float t = uv;
      #pragma unroll
      for (int off=1; off<64; off<<=1) t += __shfl_xor(t, off);
      if (lane==0) atomicAdd(&scal[S_U(k-1)], t);
    }
    float acc[8]={0,0,0,0,0,0,0,0};
    for (int r0=0; r0<64; r0+=8){
      uint2 mv[8];
      #pragma unroll
      for (int q=0;q<8;q++) mv[q] = *reinterpret_cast<const uint2*>(mp + (size_t)(r0+q)*NCC);
      #pragma unroll
      for (int q=0;q<8;q++){
        float ui = __shfl(uv, r0+q);
        float f0[4], f1[4];
        cvt4(mv[q].x, f0); cvt4(mv[q].y, f1);
        #pragma unroll
        for (int b=0;b<4;b++){
          acc[b]   = fmaf(EXP2R(fmaf(f0[b], cs, cb)), ui, acc[b]);
          acc[4+b] = fmaf(EXP2R(fmaf(f1[b], cs, cb)), ui, acc[4+b]);
        }
      }
    }
    #pragma unroll
    for (int c=0;c<8;c++) red[wave][c*64+lane] = acc[c];
    __syncthreads();
    for (int idx=tid; idx<512; idx+=256){
      float s = red[0][idx]+red[1][idx]+red[2][idx]+red[3][idx];
      atomicAdd(&tacc[jbase + (idx&63)*8 + (idx>>6)], s);
    }
    gbar(sync, tid);
    // ---- U^{k-1} complete ----
    float Up  = (k==1) ? 0.5f : aload(&scal[S_U(k-1)]);
    float wsk = 0.5f/(Ks*Up + 1.000001f*usl);      // ws^k
    float addc = 1e-6f*Up + Ks*usl;
    // ---- phase B: sacc_i += sum_j e_ij * w^k_j ; by==0&&wave==0 accumulates W^k ----
    float wv[8];
    #pragma unroll
    for (int c=0;c<8;c++) wv[c] = AB/(aload(&tacc[jbase + lane*8 + c]) + addc);
    if (by==0 && wave==0){
      float s = wv[0]+wv[1]+wv[2]+wv[3]+wv[4]+wv[5]+wv[6]+wv[7];
      #pragma unroll
      for (int off=1; off<64; off<<=1) s += __shfl_xor(s, off);
      if (lane==0) atomicAdd(&scal[S_W(k)], s);
    }
    for (int r0=0; r0<64; r0+=8){
      uint2 mv[8];
      #pragma unroll
      for (int q=0;q<8;q++) mv[q] = *reinterpret_cast<const uint2*>(mp + (size_t)(r0+q)*NCC);
      #pragma unroll
      for (int q=0;q<8;q++){
        float f0[4], f1[4];
        cvt4(mv[q].x, f0); cvt4(mv[q].y, f1);
        float d = 0.f;
        #pragma unroll
        for (int b=0;b<4;b++){
          d = fmaf(EXP2R(fmaf(f0[b], cs, cb)), wv[b], d);
          d = fmaf(EXP2R(fmaf(f1[b], cs, cb)), wv[4+b], d);
        }
        #pragma unroll
        for (int off=1; off<64; off<<=1) d += __shfl_xor(d, off);
        if (lane==0) atomicAdd(&sacc[rowbase + r0 + q], d);
      }
    }
    gbar(sync, tid);
    float Wk = aload(&scal[S_W(k)]);
    usl = 0.5f/(Ks*Wk + 1.000001f*wsk);            // us^k
    wsl = wsk;
    Wl  = Wk;
  }

  // ---- phase AE (pass 21 = A#11 + E prep): tacc11, qa=sum u*e*m, pa=sum u*m ----
  {
    float* tacc11 = accs + (size_t)10*NCC;
    float* qa = accs + (size_t)25*NCC;
    float* pa = accs + (size_t)26*NCC;
    float uv = AB/(aload(&accs[(size_t)20*NCC + rowbase + lane]) + 1e-6f*Wl + Ks*wsl);
    if (bx==0){
      float t = uv;
      #pragma unroll
      for (int off=1; off<64; off<<=1) t += __shfl_xor(t, off);
      if (lane==0) atomicAdd(&scal[S_U(10)], t);
    }
    float at[8]={0,0,0,0,0,0,0,0}, aq[8]={0,0,0,0,0,0,0,0}, ap[8]={0,0,0,0,0,0,0,0};
    for (int r0=0; r0<64; r0+=8){
      uint2 mv[8];
      #pragma unroll
      for (int q=0;q<8;q++) mv[q] = *reinterpret_cast<const uint2*>(mp + (size_t)(r0+q)*NCC);
      #pragma unroll
      for (int q=0;q<8;q++){
        float ui = __shfl(uv, r0+q);
        float f0[4], f1[4];
        cvt4(mv[q].x, f0); cvt4(mv[q].y, f1);
        #pragma unroll
        for (int b=0;b<4;b++){
          float m0 = fmaf(f0[b], QSTEP, QLO);
          float m1 = fmaf(f1[b], QSTEP, QLO);
          float e0 = EXP2R(fmaf(f0[b], cs, cb)) * ui;
          float e1 = EXP2R(fmaf(f1[b], cs, cb)) * ui;
          at[b]   += e0;                       at[4+b] += e1;
          aq[b]    = fmaf(e0, m0, aq[b]);      aq[4+b]  = fmaf(e1, m1, aq[4+b]);
          ap[b]    = fmaf(ui, m0, ap[b]);      ap[4+b]  = fmaf(ui, m1, ap[4+b]);
        }
      }
    }
    float* dsts[3] = {tacc11, qa, pa};
    float* srcs0[3] = {at, aq, ap};
    for (int rnd=0; rnd<3; rnd++){
      __syncthreads();
      #pragma unroll
      for (int c=0;c<8;c++) red[wave][c*64+lane] = srcs0[rnd][c];
      __syncthreads();
      for (int idx=tid; idx<512; idx+=256){
        float v = red[0][idx]+red[1][idx]+red[2][idx]+red[3][idx];
        atomicAdd(&dsts[rnd][jbase + (idx&63)*8 + (idx>>6)], v);
      }
    }
  }
  gbar(sync, tid);

  // ---- finalize: v_j from tacc11, E = sum v*(q+1e-6*p); by==0 WGs (16) cover all stripes ----
  float U10 = aload(&scal[S_U(10)]);
  if (by==0){
    __shared__ float er[4], vr[4];
    const float* tacc11 = accs + (size_t)10*NCC;
    const float* qa = accs + (size_t)25*NCC;
    const float* pa = accs + (size_t)26*NCC;
    float addc = 1e-6f*U10 + Ks*usl;               // usl = us^10
    float Ep = 0.f, Vp = 0.f;
    for (int j2=tid; j2<512; j2+=256){
      int j = jbase + j2;
      float vj = AB/(aload(&tacc11[j]) + addc);
      Vp += vj;
      Ep = fmaf(vj, aload(&qa[j]) + 1e-6f*aload(&pa[j]), Ep);
    }
    #pragma unroll
    for (int off=1; off<64; off<<=1){ Ep += __shfl_xor(Ep, off); Vp += __shfl_xor(Vp, off); }
    if (lane==0){ er[wave]=Ep; vr[wave]=Vp; }
    __syncthreads();
    if (tid==0){
      atomicAdd(&scal[S_E], er[0]+er[1]+er[2]+er[3]);
      atomicAdd(&scal[S_V], vr[0]+vr[1]+vr[2]+vr[3]);
    }
  }
  gbar(sync, tid);
  if (wg==0 && tid==0){
    float E = aload(&scal[S_E]), V = aload(&scal[S_V]);
    float delta = aload(&scal[S_DELTA]);
    float vs = 0.5f/(Ks*U10 + 1.000001f*usl);
    out[0] = 2.f*(E + delta*Ks*(usl*V + vs*U10));
  }
}

// ---------------- launch ----------------
extern "C" void kernel_launch(void* const* d_in, const int* in_sizes, int n_in,
                              void* d_out, int out_size, void* d_ws, size_t ws_size,
                              hipStream_t stream){
  (void)in_sizes; (void)n_in; (void)out_size; (void)ws_size;
  const float* X = (const float*)d_in[0];
  char* ws = (char*)d_ws;
  float*         scal = (float*)(ws + OFF_SCAL);
  float*         accs = (float*)(ws + OFF_ACC);
  float*         gp   = accs + (size_t)21*NCC;   // slabs 21..24
  float*         rn   = (float*)(ws + OFF_RN);
  short*         Xh   = (short*)(ws + OFF_XH);
  short*         Xl   = (short*)(ws + OFF_XL);
  unsigned char* Mq   = (unsigned char*)(ws + OFF_M);
  float*         out  = (float*)d_out;

  hipMemsetAsync(ws, 0, OFF_ACC + N_SLABS*NCC*4, stream);

  k_pack<<<NTOT/16, 256, 0, stream>>>(X, Xh, Xl, rn);
  k_gemm<<<dim3(128,128), 256, 0, stream>>>(Xh, Xl, Mq, rn, gp);
  k_sink<<<NWG, 256, 0, stream>>>(Mq, accs, scal, gp, out);
}

// Round 16
// 1872.732 us; speedup vs baseline: 1.3932x; 1.3932x over previous
//
#include <hip/hip_runtime.h>
#include <math.h>

// ---------------- problem constants ----------------
#define NTOT 16384
#define NTT  8192
#define NCC  8192
#define DIM  128
#define AB   6.103515625e-05f        // p/NT = 0.5/8192 (exact)
#define LOG2E 1.4426950408889634f
#define QLO  6.0f                    // u8 quantization range for M: [6,24]
#define QSTEP (18.0f/255.0f)
#define QSCALE (255.0f/18.0f)
#define NWG  512u                    // k_sink grid: 16 x 32; 2/CU guaranteed co-resident

#define EXP2R(x) __builtin_amdgcn_exp2f(x)
#define SQRTR(x) __builtin_amdgcn_sqrtf(x)

// ---------------- scal slots ----------------
#define S_C2    2
#define S_KS    3
#define S_DELTA 4
#define S_E     5
#define S_V     6
#define S_U(t) (8 + (t))             // U^t, t=0..10
#define S_W(t) (24 + (t))            // W^t, t=1..10
#define S_SYNC  48                   // u32 cnt @48, u32 gen @49

// ---------------- ws layout (bytes) ----------------
#define N_SLABS 27
#define OFF_SCAL 0                               // f32[256]
#define OFF_ACC  1024
#define OFF_RN   (OFF_ACC + N_SLABS*NCC*4)       // f32[16384]
#define OFF_XH   (OFF_RN + NTOT*4)               // bf16 hi fragments (4 MB)
#define OFF_XL   (OFF_XH + NTOT*DIM*2)           // bf16 lo fragments (4 MB)
#define OFF_M    (OFF_XL + NTOT*DIM*2)           // u8 M [8192*8192] (67 MB)

typedef short bf16x8 __attribute__((ext_vector_type(8)));
typedef float f32x4  __attribute__((ext_vector_type(4)));

__device__ __forceinline__ float aload(const float* p){
  return __hip_atomic_load(p, __ATOMIC_RELAXED, __HIP_MEMORY_SCOPE_AGENT);
}
__device__ __forceinline__ void cvt4(unsigned v, float* f){
  f[0] = (float)(v & 0xFFu);
  f[1] = (float)((v >> 8) & 0xFFu);
  f[2] = (float)((v >> 16) & 0xFFu);
  f[3] = (float)(v >> 24);
}

// sense-reversing grid barrier v2 (R15 post-mortem): spinners use RELAXED
// bypassing loads (NO per-poll L2 invalidation) + s_sleep backoff; exactly one
// ACQUIRE after exit. R15's ACQUIRE-spin invalidated L2 device-wide ~5x/us and
// collapsed M streaming to 356 GB/s.
__device__ __forceinline__ void gbar(unsigned* sync, int tid){
  __syncthreads();                       // drains this WG's vmem before arrival
  if (tid==0){
    unsigned g = __hip_atomic_load(&sync[1], __ATOMIC_RELAXED, __HIP_MEMORY_SCOPE_AGENT);
    unsigned old = __hip_atomic_fetch_add(&sync[0], 1u, __ATOMIC_ACQ_REL, __HIP_MEMORY_SCOPE_AGENT);
    if (old == NWG-1u){
      __hip_atomic_store(&sync[0], 0u, __ATOMIC_RELAXED, __HIP_MEMORY_SCOPE_AGENT);
      __hip_atomic_fetch_add(&sync[1], 1u, __ATOMIC_RELEASE, __HIP_MEMORY_SCOPE_AGENT);
    } else {
      while (__hip_atomic_load(&sync[1], __ATOMIC_RELAXED, __HIP_MEMORY_SCOPE_AGENT) == g)
        __builtin_amdgcn_s_sleep(32);
      (void)__hip_atomic_load(&sync[1], __ATOMIC_ACQUIRE, __HIP_MEMORY_SCOPE_AGENT); // one fence
    }
  }
  __syncthreads();
}

// ---------------- pack: X fp32 -> bf16 hi/lo MFMA-fragment layout + row norms ----------------
__global__ __launch_bounds__(256) void k_pack(const float* __restrict__ X,
                                              short* __restrict__ Xh, short* __restrict__ Xl,
                                              float* __restrict__ rn){
  int tid = threadIdx.x;
  int m = tid >> 4, c = tid & 15;
  int tile = blockIdx.x;
  int row = tile*16 + m;
  const float* src = X + (size_t)row*DIM + c*8;
  float4 f0 = *reinterpret_cast<const float4*>(src);
  float4 f1 = *reinterpret_cast<const float4*>(src + 4);
  float f[8] = {f0.x,f0.y,f0.z,f0.w,f1.x,f1.y,f1.z,f1.w};
  float ss = 0.f;
  #pragma unroll
  for (int i=0;i<8;i++) ss += f[i]*f[i];
  #pragma unroll
  for (int off=1; off<16; off<<=1) ss += __shfl_xor(ss, off);
  if (c==0) rn[row] = ss;
  bf16x8 h, l;
  #pragma unroll
  for (int i=0;i<8;i++){
    unsigned u  = __float_as_uint(f[i]);
    unsigned rh = (u + 0x7FFFu + ((u>>16)&1u)) & 0xFFFF0000u;
    h[i] = (short)(rh>>16);
    float fl = f[i] - __uint_as_float(rh);
    unsigned u2 = __float_as_uint(fl);
    l[i] = (short)((u2 + 0x7FFFu + ((u2>>16)&1u)) >> 16);
  }
  int ks = c >> 2, q = c & 3;
  size_t addr = ((size_t)((tile*4 + ks)*64) + m + 16*q)*8;
  *reinterpret_cast<bf16x8*>(Xh + addr) = h;
  *reinterpret_cast<bf16x8*>(Xl + addr) = l;
}

// ---------------- gemm: hi/lo MFMA; M=sqrt(clip); u8-quantized store; fp32 sum/max partials ----------------
__global__ __launch_bounds__(256) void k_gemm(const short* __restrict__ Xh, const short* __restrict__ Xl,
                                              unsigned char* __restrict__ Mq,
                                              const float* __restrict__ rn, float* __restrict__ gp){
  __shared__ __align__(16) unsigned char tile[64*80];
  __shared__ float ssum[4], smax[4];
  int tid=threadIdx.x, wave=tid>>6, lane=tid&63;
  int l15=lane&15, quad=lane>>4;
  int rowA = blockIdx.y*64 + (wave>>1)*32;
  int colC = blockIdx.x*64 + (wave&1)*32;
  int tA = rowA >> 4;
  int tB = (NTT + colC) >> 4;
  f32x4 acc[2][2] = {};
  #pragma unroll
  for (int ks=0; ks<4; ks++){
    bf16x8 Ah[2], Al[2], Bh[2], Bl[2];
    #pragma unroll
    for (int t=0;t<2;t++){
      size_t aA = ((size_t)(((tA+t)*4+ks)*64) + lane)*8;
      size_t aB = ((size_t)(((tB+t)*4+ks)*64) + lane)*8;
      Ah[t] = *reinterpret_cast<const bf16x8*>(Xh + aA);
      Al[t] = *reinterpret_cast<const bf16x8*>(Xl + aA);
      Bh[t] = *reinterpret_cast<const bf16x8*>(Xh + aB);
      Bl[t] = *reinterpret_cast<const bf16x8*>(Xl + aB);
    }
    #pragma unroll
    for (int ti=0;ti<2;ti++)
      #pragma unroll
      for (int tj=0;tj<2;tj++){
        acc[ti][tj] = __builtin_amdgcn_mfma_f32_16x16x32_bf16(Ah[ti], Bh[tj], acc[ti][tj],0,0,0);
        acc[ti][tj] = __builtin_amdgcn_mfma_f32_16x16x32_bf16(Ah[ti], Bl[tj], acc[ti][tj],0,0,0);
        acc[ti][tj] = __builtin_amdgcn_mfma_f32_16x16x32_bf16(Al[ti], Bh[tj], acc[ti][tj],0,0,0);
      }
  }
  float lsum = 0.f, lmax = 0.f;
  #pragma unroll
  for (int ti=0;ti<2;ti++)
    #pragma unroll
    for (int tj=0;tj<2;tj++)
      #pragma unroll
      for (int r=0;r<4;r++){
        int lr = (wave>>1)*32 + ti*16 + quad*4 + r;
        int lc = (wave&1)*32 + tj*16 + l15;
        int gr = blockIdx.y*64 + lr;
        int gc = blockIdx.x*64 + lc;
        float g  = acc[ti][tj][r];
        float d2 = fmaxf(rn[gr] - 2.f*g + rn[NTT+gc], 1e-10f);
        float m  = SQRTR(d2);
        int q = (int)fmaf(m, QSCALE, -QLO*QSCALE + 0.5f);
        q = min(max(q, 0), 255);
        tile[lr*80 + lc] = (unsigned char)q;
        lsum += m; lmax = fmaxf(lmax, m);
      }
  #pragma unroll
  for (int off=32; off; off>>=1){
    lsum += __shfl_xor(lsum, off);
    lmax  = fmaxf(lmax, __shfl_xor(lmax, off));
  }
  if (lane==0){ ssum[wave]=lsum; smax[wave]=lmax; }
  __syncthreads();
  if (tid==0){
    int wg = blockIdx.y*128 + blockIdx.x;
    gp[wg]         = ssum[0]+ssum[1]+ssum[2]+ssum[3];
    gp[16384 + wg] = fmaxf(fmaxf(smax[0],smax[1]), fmaxf(smax[2],smax[3]));
  }
  int lr = tid>>2, s16 = tid&3;
  uint4 v = *reinterpret_cast<const uint4*>(&tile[lr*80 + s16*16]);
  *reinterpret_cast<uint4*>(Mq + (size_t)(blockIdx.y*64+lr)*NCC + blockIdx.x*64 + s16*16) = v;
}

// ---------------- fused Sinkhorn: scal + 21 passes + finalize, ONE kernel, software grid barrier ----------------
__global__ __launch_bounds__(256,2) void k_sink(const unsigned char* __restrict__ Mq,
      float* __restrict__ accs, float* scal, const float* __restrict__ gp,
      float* __restrict__ out){
  __shared__ float red[4][512];
  unsigned* sync = (unsigned*)scal + S_SYNC;
  int tid=threadIdx.x, wave=tid>>6, lane=tid&63;
  int wg = blockIdx.x;
  int bx = wg & 15, by = wg >> 4;             // 16 x 32
  int jbase = bx*512, rowbase = by*256 + wave*64;

  // ---- scal phase (WG0 only) ----
  if (wg==0){
    __shared__ float sr[4], mr[4];
    float s=0.f, mx=0.f;
    for (int i=tid;i<16384;i+=256){ s+=gp[i]; mx=fmaxf(mx,gp[16384+i]); }
    #pragma unroll
    for (int off=1; off<64; off<<=1){ s+=__shfl_xor(s,off); mx=fmaxf(mx,__shfl_xor(mx,off)); }
    if (lane==0){ sr[wave]=s; mr[wave]=mx; }
    __syncthreads();
    if (tid==0){
      float Msum=sr[0]+sr[1]+sr[2]+sr[3];
      float delta=fmaxf(fmaxf(mr[0],mr[1]),fmaxf(mr[2],mr[3]));
      float c2=-(671088640.0f/Msum)*LOG2E;
      scal[S_C2]=c2; scal[S_KS]=EXP2R(c2*delta)+1e-6f; scal[S_DELTA]=delta;
    }
  }
  gbar(sync, tid);
  float c2 = aload(&scal[S_C2]), Ks = aload(&scal[S_KS]);
  float cs = c2*QSTEP, cb = c2*QLO;

  float usl = 0.5f, wsl = 0.f, Wl = 0.f;      // after iter k: us^k, ws^k, W^k
  const unsigned char* mp = Mq + (size_t)rowbase*NCC + jbase + lane*8;

  #pragma unroll 1
  for (int k=1; k<=10; ++k){
    float* tacc = accs + (size_t)(k-1)*NCC;
    float* sacc = accs + (size_t)(10+k)*NCC;
    const float* saccPrev = accs + (size_t)(10+k-1)*NCC;
    // ---- phase A: tacc_j += sum_i e_ij * u^{k-1}_i ; bx==0 accumulates U^{k-1} ----
    float uv;
    if (k==1) uv = AB;
    else      uv = AB/(aload(&saccPrev[rowbase + lane]) + 1e-6f*Wl + Ks*wsl);
    if (bx==0){
      float t = uv;
      #pragma unroll
      for (int off=1; off<64; off<<=1) t += __shfl_xor(t, off);
      if (lane==0) atomicAdd(&scal[S_U(k-1)], t);
    }
    float acc[8]={0,0,0,0,0,0,0,0};
    for (int r0=0; r0<64; r0+=8){
      uint2 mv[8];
      #pragma unroll
      for (int q=0;q<8;q++) mv[q] = *reinterpret_cast<const uint2*>(mp + (size_t)(r0+q)*NCC);
      #pragma unroll
      for (int q=0;q<8;q++){
        float ui = __shfl(uv, r0+q);
        float f0[4], f1[4];
        cvt4(mv[q].x, f0); cvt4(mv[q].y, f1);
        #pragma unroll
        for (int b=0;b<4;b++){
          acc[b]   = fmaf(EXP2R(fmaf(f0[b], cs, cb)), ui, acc[b]);
          acc[4+b] = fmaf(EXP2R(fmaf(f1[b], cs, cb)), ui, acc[4+b]);
        }
      }
    }
    #pragma unroll
    for (int c=0;c<8;c++) red[wave][c*64+lane] = acc[c];
    __syncthreads();
    for (int idx=tid; idx<512; idx+=256){
      float s = red[0][idx]+red[1][idx]+red[2][idx]+red[3][idx];
      atomicAdd(&tacc[jbase + (idx&63)*8 + (idx>>6)], s);
    }
    gbar(sync, tid);
    // ---- U^{k-1} complete ----
    float Up  = (k==1) ? 0.5f : aload(&scal[S_U(k-1)]);
    float wsk = 0.5f/(Ks*Up + 1.000001f*usl);      // ws^k
    float addc = 1e-6f*Up + Ks*usl;
    // ---- phase B: sacc_i += sum_j e_ij * w^k_j ; by==0&&wave==0 accumulates W^k ----
    float wv[8];
    #pragma unroll
    for (int c=0;c<8;c++) wv[c] = AB/(aload(&tacc[jbase + lane*8 + c]) + addc);
    if (by==0 && wave==0){
      float s = wv[0]+wv[1]+wv[2]+wv[3]+wv[4]+wv[5]+wv[6]+wv[7];
      #pragma unroll
      for (int off=1; off<64; off<<=1) s += __shfl_xor(s, off);
      if (lane==0) atomicAdd(&scal[S_W(k)], s);
    }
    for (int r0=0; r0<64; r0+=8){
      uint2 mv[8];
      #pragma unroll
      for (int q=0;q<8;q++) mv[q] = *reinterpret_cast<const uint2*>(mp + (size_t)(r0+q)*NCC);
      #pragma unroll
      for (int q=0;q<8;q++){
        float f0[4], f1[4];
        cvt4(mv[q].x, f0); cvt4(mv[q].y, f1);
        float d = 0.f;
        #pragma unroll
        for (int b=0;b<4;b++){
          d = fmaf(EXP2R(fmaf(f0[b], cs, cb)), wv[b], d);
          d = fmaf(EXP2R(fmaf(f1[b], cs, cb)), wv[4+b], d);
        }
        #pragma unroll
        for (int off=1; off<64; off<<=1) d += __shfl_xor(d, off);
        if (lane==0) atomicAdd(&sacc[rowbase + r0 + q], d);
      }
    }
    gbar(sync, tid);
    float Wk = aload(&scal[S_W(k)]);
    usl = 0.5f/(Ks*Wk + 1.000001f*wsk);            // us^k
    wsl = wsk;
    Wl  = Wk;
  }

  // ---- phase AE (pass 21 = A#11 + E prep): tacc11, qa=sum u*e*m, pa=sum u*m ----
  {
    float* tacc11 = accs + (size_t)10*NCC;
    float* qa = accs + (size_t)25*NCC;
    float* pa = accs + (size_t)26*NCC;
    float uv = AB/(aload(&accs[(size_t)20*NCC + rowbase + lane]) + 1e-6f*Wl + Ks*wsl);
    if (bx==0){
      float t = uv;
      #pragma unroll
      for (int off=1; off<64; off<<=1) t += __shfl_xor(t, off);
      if (lane==0) atomicAdd(&scal[S_U(10)], t);
    }
    float at[8]={0,0,0,0,0,0,0,0}, aq[8]={0,0,0,0,0,0,0,0}, ap[8]={0,0,0,0,0,0,0,0};
    for (int r0=0; r0<64; r0+=8){
      uint2 mv[8];
      #pragma unroll
      for (int q=0;q<8;q++) mv[q] = *reinterpret_cast<const uint2*>(mp + (size_t)(r0+q)*NCC);
      #pragma unroll
      for (int q=0;q<8;q++){
        float ui = __shfl(uv, r0+q);
        float f0[4], f1[4];
        cvt4(mv[q].x, f0); cvt4(mv[q].y, f1);
        #pragma unroll
        for (int b=0;b<4;b++){
          float m0 = fmaf(f0[b], QSTEP, QLO);
          float m1 = fmaf(f1[b], QSTEP, QLO);
          float e0 = EXP2R(fmaf(f0[b], cs, cb)) * ui;
          float e1 = EXP2R(fmaf(f1[b], cs, cb)) * ui;
          at[b]   += e0;                       at[4+b] += e1;
          aq[b]    = fmaf(e0, m0, aq[b]);      aq[4+b]  = fmaf(e1, m1, aq[4+b]);
          ap[b]    = fmaf(ui, m0, ap[b]);      ap[4+b]  = fmaf(ui, m1, ap[4+b]);
        }
      }
    }
    float* dsts[3] = {tacc11, qa, pa};
    float* srcs0[3] = {at, aq, ap};
    for (int rnd=0; rnd<3; rnd++){
      __syncthreads();
      #pragma unroll
      for (int c=0;c<8;c++) red[wave][c*64+lane] = srcs0[rnd][c];
      __syncthreads();
      for (int idx=tid; idx<512; idx+=256){
        float v = red[0][idx]+red[1][idx]+red[2][idx]+red[3][idx];
        atomicAdd(&dsts[rnd][jbase + (idx&63)*8 + (idx>>6)], v);
      }
    }
  }
  gbar(sync, tid);

  // ---- finalize: v_j from tacc11, E = sum v*(q+1e-6*p); by==0 WGs (16) cover all stripes ----
  float U10 = aload(&scal[S_U(10)]);
  if (by==0){
    __shared__ float er[4], vr[4];
    const float* tacc11 = accs + (size_t)10*NCC;
    const float* qa = accs + (size_t)25*NCC;
    const float* pa = accs + (size_t)26*NCC;
    float addc = 1e-6f*U10 + Ks*usl;               // usl = us^10
    float Ep = 0.f, Vp = 0.f;
    for (int j2=tid; j2<512; j2+=256){
      int j = jbase + j2;
      float vj = AB/(aload(&tacc11[j]) + addc);
      Vp += vj;
      Ep = fmaf(vj, aload(&qa[j]) + 1e-6f*aload(&pa[j]), Ep);
    }
    #pragma unroll
    for (int off=1; off<64; off<<=1){ Ep += __shfl_xor(Ep, off); Vp += __shfl_xor(Vp, off); }
    if (lane==0){ er[wave]=Ep; vr[wave]=Vp; }
    __syncthreads();
    if (tid==0){
      atomicAdd(&scal[S_E], er[0]+er[1]+er[2]+er[3]);
      atomicAdd(&scal[S_V], vr[0]+vr[1]+vr[2]+vr[3]);
    }
  }
  gbar(sync, tid);
  if (wg==0 && tid==0){
    float E = aload(&scal[S_E]), V = aload(&scal[S_V]);
    float delta = aload(&scal[S_DELTA]);
    float vs = 0.5f/(Ks*U10 + 1.000001f*usl);
    out[0] = 2.f*(E + delta*Ks*(usl*V + vs*U10));
  }
}

// ---------------- launch ----------------
extern "C" void kernel_launch(void* const* d_in, const int* in_sizes, int n_in,
                              void* d_out, int out_size, void* d_ws, size_t ws_size,
                              hipStream_t stream){
  (void)in_sizes; (void)n_in; (void)out_size; (void)ws_size;
  const float* X = (const float*)d_in[0];
  char* ws = (char*)d_ws;
  float*         scal = (float*)(ws + OFF_SCAL);
  float*         accs = (float*)(ws + OFF_ACC);
  float*         gp   = accs + (size_t)21*NCC;   // slabs 21..24
  float*         rn   = (float*)(ws + OFF_RN);
  short*         Xh   = (short*)(ws + OFF_XH);
  short*         Xl   = (short*)(ws + OFF_XL);
  unsigned char* Mq   = (unsigned char*)(ws + OFF_M);
  float*         out  = (float*)d_out;

  hipMemsetAsync(ws, 0, OFF_ACC + N_SLABS*NCC*4, stream);

  k_pack<<<NTOT/16, 256, 0, stream>>>(X, Xh, Xl, rn);
  k_gemm<<<dim3(128,128), 256, 0, stream>>>(Xh, Xl, Mq, rn, gp);
  k_sink<<<NWG, 256, 0, stream>>>(Mq, accs, scal, gp, out);
}

// Round 17
// 1388.221 us; speedup vs baseline: 1.8795x; 1.3490x over previous
//
#include <hip/hip_runtime.h>
#include <math.h>

// ---------------- problem constants ----------------
#define NTOT 16384
#define NTT  8192
#define NCC  8192
#define DIM  128
#define AB   6.103515625e-05f        // p/NT = 0.5/8192 (exact)
#define LOG2E 1.4426950408889634f
#define QLO  6.0f                    // u8 quantization range for M: [6,24]
#define QSTEP (18.0f/255.0f)
#define QSCALE (255.0f/18.0f)

// raw HW transcendentals: exponents in [-35,-6], no denormal fixup needed
#define EXP2R(x) __builtin_amdgcn_exp2f(x)
#define SQRTR(x) __builtin_amdgcn_sqrtf(x)

// ---------------- scal slots ----------------
#define S_C2    2
#define S_KS    3
#define S_DELTA 4
#define S_U(t) (8 + (t))             // U^t, t=0..10
#define S_W(t) (24 + (t))            // W^t, t=1..10

// ---------------- ws layout (bytes) ----------------
// slabs: tacc k -> slab k-1 (0..10); sacc k -> slab 10+k (11..20);
// slabs 21..24 = gemm partials gp[32768]; slab 25 = qa; slab 26 = pa
#define N_SLABS 27
#define OFF_SCAL 0                               // f32[256]
#define OFF_ACC  1024
#define OFF_RN   (OFF_ACC + N_SLABS*NCC*4)       // f32[16384]
#define OFF_XH   (OFF_RN + NTOT*4)               // bf16 hi fragments (4 MB)
#define OFF_XL   (OFF_XH + NTOT*DIM*2)           // bf16 lo fragments (4 MB)
#define OFF_M    (OFF_XL + NTOT*DIM*2)           // u8 M [8192*8192] (67 MB)

typedef short bf16x8 __attribute__((ext_vector_type(8)));
typedef float f32x4  __attribute__((ext_vector_type(4)));

// slack-scalar recurrence
__device__ __forceinline__ void chain(const float* scal, float Ks, int k,
                                      float& Wp, float& wsp, float& Up, float& usp){
  float us = 0.5f, U = 0.5f, ws = 0.f, W = 0.f;
  for (int t=1; t<k; t++){
    ws = 0.5f/(Ks*U + 1.000001f*us);
    W  = scal[S_W(t)];
    us = 0.5f/(Ks*W + 1.000001f*ws);
    U  = scal[S_U(t)];
  }
  Wp = W; wsp = ws; Up = U; usp = us;
}

__device__ __forceinline__ void cvt4(unsigned v, float* f){
  f[0] = (float)(v & 0xFFu);
  f[1] = (float)((v >> 8) & 0xFFu);
  f[2] = (float)((v >> 16) & 0xFFu);
  f[3] = (float)(v >> 24);
}
__device__ __forceinline__ void cvt16(uint4 v, float* f){
  cvt4(v.x, f); cvt4(v.y, f+4); cvt4(v.z, f+8); cvt4(v.w, f+12);
}

// ---------------- pack: X fp32 -> bf16 hi/lo MFMA-fragment layout + row norms ----------------
__global__ __launch_bounds__(256) void k_pack(const float* __restrict__ X,
                                              short* __restrict__ Xh, short* __restrict__ Xl,
                                              float* __restrict__ rn){
  int tid = threadIdx.x;
  int m = tid >> 4, c = tid & 15;
  int tile = blockIdx.x;
  int row = tile*16 + m;
  const float* src = X + (size_t)row*DIM + c*8;
  float4 f0 = *reinterpret_cast<const float4*>(src);
  float4 f1 = *reinterpret_cast<const float4*>(src + 4);
  float f[8] = {f0.x,f0.y,f0.z,f0.w,f1.x,f1.y,f1.z,f1.w};
  float ss = 0.f;
  #pragma unroll
  for (int i=0;i<8;i++) ss += f[i]*f[i];
  #pragma unroll
  for (int off=1; off<16; off<<=1) ss += __shfl_xor(ss, off);
  if (c==0) rn[row] = ss;
  bf16x8 h, l;
  #pragma unroll
  for (int i=0;i<8;i++){
    unsigned u  = __float_as_uint(f[i]);
    unsigned rh = (u + 0x7FFFu + ((u>>16)&1u)) & 0xFFFF0000u;
    h[i] = (short)(rh>>16);
    float fl = f[i] - __uint_as_float(rh);
    unsigned u2 = __float_as_uint(fl);
    l[i] = (short)((u2 + 0x7FFFu + ((u2>>16)&1u)) >> 16);
  }
  int ks = c >> 2, q = c & 3;
  size_t addr = ((size_t)((tile*4 + ks)*64) + m + 16*q)*8;
  *reinterpret_cast<bf16x8*>(Xh + addr) = h;
  *reinterpret_cast<bf16x8*>(Xl + addr) = l;
}

// ---------------- gemm: hi/lo MFMA; M=sqrt(clip); u8-quantized store; fp32 sum/max partials ----------------
__global__ __launch_bounds__(256) void k_gemm(const short* __restrict__ Xh, const short* __restrict__ Xl,
                                              unsigned char* __restrict__ Mq,
                                              const float* __restrict__ rn, float* __restrict__ gp){
  __shared__ __align__(16) unsigned char tile[64*80];
  __shared__ float ssum[4], smax[4];
  int tid=threadIdx.x, wave=tid>>6, lane=tid&63;
  int l15=lane&15, quad=lane>>4;
  int rowA = blockIdx.y*64 + (wave>>1)*32;
  int colC = blockIdx.x*64 + (wave&1)*32;
  int tA = rowA >> 4;
  int tB = (NTT + colC) >> 4;
  f32x4 acc[2][2] = {};
  #pragma unroll
  for (int ks=0; ks<4; ks++){
    bf16x8 Ah[2], Al[2], Bh[2], Bl[2];
    #pragma unroll
    for (int t=0;t<2;t++){
      size_t aA = ((size_t)(((tA+t)*4+ks)*64) + lane)*8;
      size_t aB = ((size_t)(((tB+t)*4+ks)*64) + lane)*8;
      Ah[t] = *reinterpret_cast<const bf16x8*>(Xh + aA);
      Al[t] = *reinterpret_cast<const bf16x8*>(Xl + aA);
      Bh[t] = *reinterpret_cast<const bf16x8*>(Xh + aB);
      Bl[t] = *reinterpret_cast<const bf16x8*>(Xl + aB);
    }
    #pragma unroll
    for (int ti=0;ti<2;ti++)
      #pragma unroll
      for (int tj=0;tj<2;tj++){
        acc[ti][tj] = __builtin_amdgcn_mfma_f32_16x16x32_bf16(Ah[ti], Bh[tj], acc[ti][tj],0,0,0);
        acc[ti][tj] = __builtin_amdgcn_mfma_f32_16x16x32_bf16(Ah[ti], Bl[tj], acc[ti][tj],0,0,0);
        acc[ti][tj] = __builtin_amdgcn_mfma_f32_16x16x32_bf16(Al[ti], Bh[tj], acc[ti][tj],0,0,0);
      }
  }
  float lsum = 0.f, lmax = 0.f;
  #pragma unroll
  for (int ti=0;ti<2;ti++)
    #pragma unroll
    for (int tj=0;tj<2;tj++)
      #pragma unroll
      for (int r=0;r<4;r++){
        int lr = (wave>>1)*32 + ti*16 + quad*4 + r;
        int lc = (wave&1)*32 + tj*16 + l15;
        int gr = blockIdx.y*64 + lr;
        int gc = blockIdx.x*64 + lc;
        float g  = acc[ti][tj][r];
        float d2 = fmaxf(rn[gr] - 2.f*g + rn[NTT+gc], 1e-10f);
        float m  = SQRTR(d2);
        int q = (int)fmaf(m, QSCALE, -QLO*QSCALE + 0.5f);
        q = min(max(q, 0), 255);
        tile[lr*80 + lc] = (unsigned char)q;
        lsum += m; lmax = fmaxf(lmax, m);
      }
  #pragma unroll
  for (int off=32; off; off>>=1){
    lsum += __shfl_xor(lsum, off);
    lmax  = fmaxf(lmax, __shfl_xor(lmax, off));
  }
  if (lane==0){ ssum[wave]=lsum; smax[wave]=lmax; }
  __syncthreads();
  if (tid==0){
    int wg = blockIdx.y*128 + blockIdx.x;
    gp[wg]         = ssum[0]+ssum[1]+ssum[2]+ssum[3];
    gp[16384 + wg] = fmaxf(fmaxf(smax[0],smax[1]), fmaxf(smax[2],smax[3]));
  }
  int lr = tid>>2, s16 = tid&3;
  uint4 v = *reinterpret_cast<const uint4*>(&tile[lr*80 + s16*16]);
  *reinterpret_cast<uint4*>(Mq + (size_t)(blockIdx.y*64+lr)*NCC + blockIdx.x*64 + s16*16) = v;
}

// ---------------- scal: reduce gemm partials, precompute c2/Ks/delta ----------------
__global__ __launch_bounds__(256) void k_scal(const float* __restrict__ gp, float* scal){
  int tid=threadIdx.x, wave=tid>>6, lane=tid&63;
  float s = 0.f, mx = 0.f;
  for (int i=tid; i<16384; i+=256){
    s  += gp[i];
    mx  = fmaxf(mx, gp[16384 + i]);
  }
  #pragma unroll
  for (int off=1; off<64; off<<=1){
    s  += __shfl_xor(s, off);
    mx  = fmaxf(mx, __shfl_xor(mx, off));
  }
  __shared__ float sr[4], mr[4];
  if (lane==0){ sr[wave]=s; mr[wave]=mx; }
  __syncthreads();
  if (tid==0){
    float Msum  = sr[0]+sr[1]+sr[2]+sr[3];
    float delta = fmaxf(fmaxf(mr[0],mr[1]), fmaxf(mr[2],mr[3]));
    float c2 = -(671088640.0f/Msum)*LOG2E;
    scal[S_C2]    = c2;
    scal[S_KS]    = EXP2R(c2*delta) + 1e-6f;
    scal[S_DELTA] = delta;
  }
}

// ---------------- pass A #k: tacc_j += sum_i e_ij*u_i ----------------
// uint4 M loads: 16 cols/lane, 1024-col stripes, 16 rows/wave, 8-row batches
// => 128 B in flight per lane (2x R12's uint2) -- memory-latency-parallelism fix.
// grid (8,128) = 1024 WGs = 4/CU. VGPR: acc16+mv32+temps ~80 < 128 cap (256,4).
__global__ __launch_bounds__(256,4) void k_passA(const unsigned char* __restrict__ Mq,
      const float* __restrict__ saccPrev, float* __restrict__ tacc,
      float* scal, int k){
  int tid=threadIdx.x, wave=tid>>6, lane=tid&63;
  int jbase = blockIdx.x*1024, rowbase = blockIdx.y*64 + wave*16;
  float c2 = scal[S_C2], Ks = scal[S_KS];
  float cs = c2*QSTEP, cb = c2*QLO;
  float Wp, wsp, Up, usp; chain(scal, Ks, k, Wp, wsp, Up, usp);
  float uv;
  if (k==1) uv = AB;
  else {
    float s = saccPrev[rowbase + (lane&15)];
    uv = AB/(s + 1e-6f*Wp + Ks*wsp);
  }
  if (blockIdx.x==0){                  // 16 distinct rows per wave (lanes 0..15)
    float t = uv;
    #pragma unroll
    for (int off=1; off<16; off<<=1) t += __shfl_xor(t, off);
    if (lane==0) atomicAdd(&scal[S_U(k-1)], t);
  }
  float acc[16];
  #pragma unroll
  for (int c=0;c<16;c++) acc[c]=0.f;
  const unsigned char* mp = Mq + (size_t)rowbase*NCC + jbase + lane*16;
  for (int r0=0; r0<16; r0+=8){
    uint4 mv[8];
    #pragma unroll
    for (int q=0;q<8;q++) mv[q] = *reinterpret_cast<const uint4*>(mp + (size_t)(r0+q)*NCC);
    #pragma unroll
    for (int q=0;q<8;q++){
      float ui = __shfl(uv, r0+q);     // lane r0+q (<16) holds row rowbase+r0+q
      float f[16]; cvt16(mv[q], f);
      #pragma unroll
      for (int b=0;b<16;b++)
        acc[b] = fmaf(EXP2R(fmaf(f[b], cs, cb)), ui, acc[b]);
    }
  }
  __shared__ float red[4][1024];
  #pragma unroll
  for (int c=0;c<16;c++) red[wave][c*64+lane] = acc[c];
  __syncthreads();
  for (int idx=tid; idx<1024; idx+=256){
    float s = red[0][idx]+red[1][idx]+red[2][idx]+red[3][idx];
    atomicAdd(&tacc[jbase + (idx&63)*16 + (idx>>6)], s);
  }
}

// ---------------- pass B #k: sacc_i += sum_j e_ij*w_j (uint4, 16 cols/lane) ----------------
__global__ __launch_bounds__(256,4) void k_passB(const unsigned char* __restrict__ Mq,
      const float* __restrict__ tacc, float* __restrict__ sacc,
      float* scal, int k){
  int tid=threadIdx.x, wave=tid>>6, lane=tid&63;
  int jbase = blockIdx.x*1024, rowbase = blockIdx.y*64 + wave*16;
  float c2 = scal[S_C2], Ks = scal[S_KS];
  float cs = c2*QSTEP, cb = c2*QLO;
  float Wp, wsp, Up, usp; chain(scal, Ks, k, Wp, wsp, Up, usp);
  float addc = 1e-6f*Up + Ks*usp;
  const float* tp = tacc + jbase + lane*16;
  float wv[16];
  #pragma unroll
  for (int d4=0; d4<4; d4++){
    float4 t4 = *reinterpret_cast<const float4*>(tp + d4*4);
    wv[d4*4+0] = AB/(t4.x+addc); wv[d4*4+1] = AB/(t4.y+addc);
    wv[d4*4+2] = AB/(t4.z+addc); wv[d4*4+3] = AB/(t4.w+addc);
  }
  if (blockIdx.y==0 && wave==0){       // 64 lanes x 16 = 1024 distinct cols
    float s = 0.f;
    #pragma unroll
    for (int c=0;c<16;c++) s += wv[c];
    #pragma unroll
    for (int off=1; off<64; off<<=1) s += __shfl_xor(s, off);
    if (lane==0) atomicAdd(&scal[S_W(k)], s);
  }
  const unsigned char* mp = Mq + (size_t)rowbase*NCC + jbase + lane*16;
  for (int r0=0; r0<16; r0+=8){
    uint4 mv[8];
    #pragma unroll
    for (int q=0;q<8;q++) mv[q] = *reinterpret_cast<const uint4*>(mp + (size_t)(r0+q)*NCC);
    #pragma unroll
    for (int q=0;q<8;q++){
      float f[16]; cvt16(mv[q], f);
      float d = 0.f;
      #pragma unroll
      for (int b=0;b<16;b++)
        d = fmaf(EXP2R(fmaf(f[b], cs, cb)), wv[b], d);
      #pragma unroll
      for (int off=1; off<64; off<<=1) d += __shfl_xor(d, off);
      if (lane==0) atomicAdd(&sacc[rowbase + r0 + q], d);
    }
  }
}

// ---------------- pass 21 (A, k=11) fused with E prep: t_j, q_j=sum u*e*m, p_j=sum u*m ----------------
// (R12-proven version, uint2/512-wide -- only 1 of 21 passes, keep VGPR-safe)
__global__ __launch_bounds__(256,4) void k_passAE(const unsigned char* __restrict__ Mq,
      const float* __restrict__ saccPrev, float* __restrict__ tacc,
      float* __restrict__ qa, float* __restrict__ pa, float* scal){
  const int k = 11;
  int tid=threadIdx.x, wave=tid>>6, lane=tid&63;
  int jbase = blockIdx.x*512, rowbase = blockIdx.y*128 + wave*32;
  float c2 = scal[S_C2], Ks = scal[S_KS];
  float cs = c2*QSTEP, cb = c2*QLO;
  float Wp, wsp, Up, usp; chain(scal, Ks, k, Wp, wsp, Up, usp);
  float s = saccPrev[rowbase + (lane&31)];
  float uv = AB/(s + 1e-6f*Wp + Ks*wsp);
  if (blockIdx.x==0){
    float t = uv;
    #pragma unroll
    for (int off=1; off<32; off<<=1) t += __shfl_xor(t, off);
    if (lane==0) atomicAdd(&scal[S_U(k-1)], t);
  }
  float at[8]={0,0,0,0,0,0,0,0}, aq[8]={0,0,0,0,0,0,0,0}, ap[8]={0,0,0,0,0,0,0,0};
  const unsigned char* mp = Mq + (size_t)rowbase*NCC + jbase + lane*8;
  for (int r0=0; r0<32; r0+=8){
    uint2 mv[8];
    #pragma unroll
    for (int q=0;q<8;q++) mv[q] = *reinterpret_cast<const uint2*>(mp + (size_t)(r0+q)*NCC);
    #pragma unroll
    for (int q=0;q<8;q++){
      float ui = __shfl(uv, r0+q);
      float f0[4], f1[4];
      cvt4(mv[q].x, f0); cvt4(mv[q].y, f1);
      #pragma unroll
      for (int b=0;b<4;b++){
        float m0 = fmaf(f0[b], QSTEP, QLO);
        float m1 = fmaf(f1[b], QSTEP, QLO);
        float e0 = EXP2R(fmaf(f0[b], cs, cb)) * ui;
        float e1 = EXP2R(fmaf(f1[b], cs, cb)) * ui;
        at[b]   += e0;                       at[4+b] += e1;
        aq[b]    = fmaf(e0, m0, aq[b]);      aq[4+b]  = fmaf(e1, m1, aq[4+b]);
        ap[b]    = fmaf(ui, m0, ap[b]);      ap[4+b]  = fmaf(ui, m1, ap[4+b]);
      }
    }
  }
  __shared__ float red[4][512];
  #pragma unroll
  for (int c=0;c<8;c++) red[wave][c*64+lane] = at[c];
  __syncthreads();
  for (int idx=tid; idx<512; idx+=256){
    float v = red[0][idx]+red[1][idx]+red[2][idx]+red[3][idx];
    atomicAdd(&tacc[jbase + (idx&63)*8 + (idx>>6)], v);
  }
  __syncthreads();
  #pragma unroll
  for (int c=0;c<8;c++) red[wave][c*64+lane] = aq[c];
  __syncthreads();
  for (int idx=tid; idx<512; idx+=256){
    float v = red[0][idx]+red[1][idx]+red[2][idx]+red[3][idx];
    atomicAdd(&qa[jbase + (idx&63)*8 + (idx>>6)], v);
  }
  __syncthreads();
  #pragma unroll
  for (int c=0;c<8;c++) red[wave][c*64+lane] = ap[c];
  __syncthreads();
  for (int idx=tid; idx<512; idx+=256){
    float v = red[0][idx]+red[1][idx]+red[2][idx]+red[3][idx];
    atomicAdd(&pa[jbase + (idx&63)*8 + (idx>>6)], v);
  }
}

// ---------------- final: v_j from t^11, E = sum v*(q+1e-6*p), slack terms, output ----------------
__global__ __launch_bounds__(256) void k_out(const float* __restrict__ tacc11,
      const float* __restrict__ qa, const float* __restrict__ pa,
      const float* scal, float* __restrict__ out){
  int tid=threadIdx.x, wave=tid>>6, lane=tid&63;
  float Ks = scal[S_KS], delta = scal[S_DELTA];
  float Wp, wsp, Up, usp; chain(scal, Ks, 11, Wp, wsp, Up, usp);
  float addc = 1e-6f*Up + Ks*usp;
  float Epart = 0.f, Vpart = 0.f;
  for (int j=tid; j<NCC; j+=256){
    float vj = AB/(tacc11[j] + addc);
    Vpart += vj;
    Epart = fmaf(vj, qa[j] + 1e-6f*pa[j], Epart);
  }
  #pragma unroll
  for (int off=1; off<64; off<<=1){
    Epart += __shfl_xor(Epart, off);
    Vpart += __shfl_xor(Vpart, off);
  }
  __shared__ float er[4], vr[4];
  if (lane==0){ er[wave]=Epart; vr[wave]=Vpart; }
  __syncthreads();
  if (tid==0){
    float E = er[0]+er[1]+er[2]+er[3];
    float V = vr[0]+vr[1]+vr[2]+vr[3];
    float vs = 0.5f/(Ks*Up + 1.000001f*usp);
    out[0] = 2.f*(E + delta*Ks*(usp*V + vs*Up));
  }
}

// ---------------- launch ----------------
extern "C" void kernel_launch(void* const* d_in, const int* in_sizes, int n_in,
                              void* d_out, int out_size, void* d_ws, size_t ws_size,
                              hipStream_t stream){
  (void)in_sizes; (void)n_in; (void)out_size; (void)ws_size;
  const float* X = (const float*)d_in[0];
  char* ws = (char*)d_ws;
  float*         scal = (float*)(ws + OFF_SCAL);
  float*         accs = (float*)(ws + OFF_ACC);
  float*         gp   = accs + (size_t)21*NCC;   // slabs 21..24
  float*         qa   = accs + (size_t)25*NCC;   // slab 25
  float*         pa   = accs + (size_t)26*NCC;   // slab 26
  float*         rn   = (float*)(ws + OFF_RN);
  short*         Xh   = (short*)(ws + OFF_XH);
  short*         Xl   = (short*)(ws + OFF_XL);
  unsigned char* Mq   = (unsigned char*)(ws + OFF_M);
  float*         out  = (float*)d_out;

  hipMemsetAsync(ws, 0, OFF_ACC + N_SLABS*NCC*4, stream);

  k_pack<<<NTOT/16, 256, 0, stream>>>(X, Xh, Xl, rn);
  k_gemm<<<dim3(128,128), 256, 0, stream>>>(Xh, Xl, Mq, rn, gp);
  k_scal<<<1, 256, 0, stream>>>(gp, scal);

  for (int k=1; k<=10; ++k){
    k_passA<<<dim3(8,128), 256, 0, stream>>>(Mq, accs + (size_t)(10+k-1)*NCC, accs + (size_t)(k-1)*NCC, scal, k);
    k_passB<<<dim3(8,128), 256, 0, stream>>>(Mq, accs + (size_t)(k-1)*NCC,   accs + (size_t)(10+k)*NCC, scal, k);
  }
  k_passAE<<<dim3(16,64), 256, 0, stream>>>(Mq, accs + (size_t)20*NCC, accs + (size_t)10*NCC, qa, pa, scal);
  k_out<<<1, 256, 0, stream>>>(accs + (size_t)10*NCC, qa, pa, scal, out);
}

// Round 18
// 543.411 us; speedup vs baseline: 4.8014x; 2.5546x over previous
//
#include <hip/hip_runtime.h>
#include <math.h>

// ---------------- problem constants ----------------
#define NTOT 16384
#define NTT  8192
#define NCC  8192
#define DIM  128
#define AB   6.103515625e-05f        // p/NT = 0.5/8192 (exact)
#define LOG2E 1.4426950408889634f
#define QLO  6.0f                    // u8 quantization range for M: [6,24]
#define QSTEP (18.0f/255.0f)
#define QSCALE (255.0f/18.0f)

#define EXP2R(x) __builtin_amdgcn_exp2f(x)
#define SQRTR(x) __builtin_amdgcn_sqrtf(x)

// ---------------- scal slots ----------------
#define S_C2    2
#define S_KS    3
#define S_DELTA 4
#define S_U(t) (8 + (t))             // U^t, t=0..10
#define S_W(t) (24 + (t))            // W^t, t=1..10

// ---------------- ws layout (bytes) ----------------
// slabs: tacc k -> slab k-1 (0..10); sacc k -> slab 10+k (11..20);
// slabs 21..24 = gemm partials gp[32768]; slab 25 = qa; slab 26 = pa
#define N_SLABS 27
#define OFF_SCAL 0                               // f32[256]
#define OFF_ACC  1024
#define OFF_RN   (OFF_ACC + N_SLABS*NCC*4)       // f32[16384]
#define OFF_XH   (OFF_RN + NTOT*4)               // bf16 hi fragments (4 MB)
#define OFF_XL   (OFF_XH + NTOT*DIM*2)           // bf16 lo fragments (4 MB)
#define OFF_M    (OFF_XL + NTOT*DIM*2)           // u8 M   [8192*8192] (67 MB)
#define OFF_MT   (OFF_M + (size_t)NTT*NCC)       // u8 M^T [8192*8192] (67 MB); total ~143.6 MB

typedef short bf16x8 __attribute__((ext_vector_type(8)));
typedef float f32x4  __attribute__((ext_vector_type(4)));

// slack-scalar recurrence
__device__ __forceinline__ void chain(const float* scal, float Ks, int k,
                                      float& Wp, float& wsp, float& Up, float& usp){
  float us = 0.5f, U = 0.5f, ws = 0.f, W = 0.f;
  for (int t=1; t<k; t++){
    ws = 0.5f/(Ks*U + 1.000001f*us);
    W  = scal[S_W(t)];
    us = 0.5f/(Ks*W + 1.000001f*ws);
    U  = scal[S_U(t)];
  }
  Wp = W; wsp = ws; Up = U; usp = us;
}

__device__ __forceinline__ void cvt4(unsigned v, float* f){
  f[0] = (float)(v & 0xFFu);
  f[1] = (float)((v >> 8) & 0xFFu);
  f[2] = (float)((v >> 16) & 0xFFu);
  f[3] = (float)(v >> 24);
}
__device__ __forceinline__ void cvt16(uint4 v, float* f){
  cvt4(v.x, f); cvt4(v.y, f+4); cvt4(v.z, f+8); cvt4(v.w, f+12);
}

// ---------------- pack: X fp32 -> bf16 hi/lo MFMA-fragment layout + row norms ----------------
__global__ __launch_bounds__(256) void k_pack(const float* __restrict__ X,
                                              short* __restrict__ Xh, short* __restrict__ Xl,
                                              float* __restrict__ rn){
  int tid = threadIdx.x;
  int m = tid >> 4, c = tid & 15;
  int tile = blockIdx.x;
  int row = tile*16 + m;
  const float* src = X + (size_t)row*DIM + c*8;
  float4 f0 = *reinterpret_cast<const float4*>(src);
  float4 f1 = *reinterpret_cast<const float4*>(src + 4);
  float f[8] = {f0.x,f0.y,f0.z,f0.w,f1.x,f1.y,f1.z,f1.w};
  float ss = 0.f;
  #pragma unroll
  for (int i=0;i<8;i++) ss += f[i]*f[i];
  #pragma unroll
  for (int off=1; off<16; off<<=1) ss += __shfl_xor(ss, off);
  if (c==0) rn[row] = ss;
  bf16x8 h, l;
  #pragma unroll
  for (int i=0;i<8;i++){
    unsigned u  = __float_as_uint(f[i]);
    unsigned rh = (u + 0x7FFFu + ((u>>16)&1u)) & 0xFFFF0000u;
    h[i] = (short)(rh>>16);
    float fl = f[i] - __uint_as_float(rh);
    unsigned u2 = __float_as_uint(fl);
    l[i] = (short)((u2 + 0x7FFFu + ((u2>>16)&1u)) >> 16);
  }
  int ks = c >> 2, q = c & 3;
  size_t addr = ((size_t)((tile*4 + ks)*64) + m + 16*q)*8;
  *reinterpret_cast<bf16x8*>(Xh + addr) = h;
  *reinterpret_cast<bf16x8*>(Xl + addr) = l;
}

// ---------------- gemm: hi/lo MFMA; u8 M AND M^T stores; fp32 sum/max partials ----------------
__global__ __launch_bounds__(256) void k_gemm(const short* __restrict__ Xh, const short* __restrict__ Xl,
                                              unsigned char* __restrict__ Mq, unsigned char* __restrict__ Mt,
                                              const float* __restrict__ rn, float* __restrict__ gp){
  __shared__ __align__(16) unsigned char tile[64*80];
  __shared__ float ssum[4], smax[4];
  int tid=threadIdx.x, wave=tid>>6, lane=tid&63;
  int l15=lane&15, quad=lane>>4;
  int rowA = blockIdx.y*64 + (wave>>1)*32;
  int colC = blockIdx.x*64 + (wave&1)*32;
  int tA = rowA >> 4;
  int tB = (NTT + colC) >> 4;
  f32x4 acc[2][2] = {};
  #pragma unroll
  for (int ks=0; ks<4; ks++){
    bf16x8 Ah[2], Al[2], Bh[2], Bl[2];
    #pragma unroll
    for (int t=0;t<2;t++){
      size_t aA = ((size_t)(((tA+t)*4+ks)*64) + lane)*8;
      size_t aB = ((size_t)(((tB+t)*4+ks)*64) + lane)*8;
      Ah[t] = *reinterpret_cast<const bf16x8*>(Xh + aA);
      Al[t] = *reinterpret_cast<const bf16x8*>(Xl + aA);
      Bh[t] = *reinterpret_cast<const bf16x8*>(Xh + aB);
      Bl[t] = *reinterpret_cast<const bf16x8*>(Xl + aB);
    }
    #pragma unroll
    for (int ti=0;ti<2;ti++)
      #pragma unroll
      for (int tj=0;tj<2;tj++){
        acc[ti][tj] = __builtin_amdgcn_mfma_f32_16x16x32_bf16(Ah[ti], Bh[tj], acc[ti][tj],0,0,0);
        acc[ti][tj] = __builtin_amdgcn_mfma_f32_16x16x32_bf16(Ah[ti], Bl[tj], acc[ti][tj],0,0,0);
        acc[ti][tj] = __builtin_amdgcn_mfma_f32_16x16x32_bf16(Al[ti], Bh[tj], acc[ti][tj],0,0,0);
      }
  }
  float lsum = 0.f, lmax = 0.f;
  #pragma unroll
  for (int ti=0;ti<2;ti++)
    #pragma unroll
    for (int tj=0;tj<2;tj++)
      #pragma unroll
      for (int r=0;r<4;r++){
        int lr = (wave>>1)*32 + ti*16 + quad*4 + r;
        int lc = (wave&1)*32 + tj*16 + l15;
        int gr = blockIdx.y*64 + lr;
        int gc = blockIdx.x*64 + lc;
        float g  = acc[ti][tj][r];
        float d2 = fmaxf(rn[gr] - 2.f*g + rn[NTT+gc], 1e-10f);
        float m  = SQRTR(d2);
        int q = (int)fmaf(m, QSCALE, -QLO*QSCALE + 0.5f);
        q = min(max(q, 0), 255);
        tile[lr*80 + lc] = (unsigned char)q;
        lsum += m; lmax = fmaxf(lmax, m);
      }
  #pragma unroll
  for (int off=32; off; off>>=1){
    lsum += __shfl_xor(lsum, off);
    lmax  = fmaxf(lmax, __shfl_xor(lmax, off));
  }
  if (lane==0){ ssum[wave]=lsum; smax[wave]=lmax; }
  __syncthreads();
  if (tid==0){
    int wg = blockIdx.y*128 + blockIdx.x;
    gp[wg]         = ssum[0]+ssum[1]+ssum[2]+ssum[3];
    gp[16384 + wg] = fmaxf(fmaxf(smax[0],smax[1]), fmaxf(smax[2],smax[3]));
  }
  // M store: thread t handles M row tid>>2, 16B chunk tid&3
  {
    int lr = tid>>2, s16 = tid&3;
    uint4 v = *reinterpret_cast<const uint4*>(&tile[lr*80 + s16*16]);
    *reinterpret_cast<uint4*>(Mq + (size_t)(blockIdx.y*64+lr)*NCC + blockIdx.x*64 + s16*16) = v;
  }
  // M^T store: thread t handles MT row (bx*64 + tid>>2), 16B chunk tid&3 (column read from LDS)
  {
    int mtr = tid>>2, s16 = tid&3;
    union { unsigned char b[16]; uint4 v; } pk;
    #pragma unroll
    for (int i=0;i<16;i++) pk.b[i] = tile[(s16*16+i)*80 + mtr];
    *reinterpret_cast<uint4*>(Mt + (size_t)(blockIdx.x*64+mtr)*NCC + blockIdx.y*64 + s16*16) = pk.v;
  }
}

// ---------------- scal: reduce gemm partials, precompute c2/Ks/delta ----------------
__global__ __launch_bounds__(256) void k_scal(const float* __restrict__ gp, float* scal){
  int tid=threadIdx.x, wave=tid>>6, lane=tid&63;
  float s = 0.f, mx = 0.f;
  for (int i=tid; i<16384; i+=256){
    s  += gp[i];
    mx  = fmaxf(mx, gp[16384 + i]);
  }
  #pragma unroll
  for (int off=1; off<64; off<<=1){
    s  += __shfl_xor(s, off);
    mx  = fmaxf(mx, __shfl_xor(mx, off));
  }
  __shared__ float sr[4], mr[4];
  if (lane==0){ sr[wave]=s; mr[wave]=mx; }
  __syncthreads();
  if (tid==0){
    float Msum  = sr[0]+sr[1]+sr[2]+sr[3];
    float delta = fmaxf(fmaxf(mr[0],mr[1]), fmaxf(mr[2],mr[3]));
    float c2 = -(671088640.0f/Msum)*LOG2E;
    scal[S_C2]    = c2;
    scal[S_KS]    = EXP2R(c2*delta) + 1e-6f;
    scal[S_DELTA] = delta;
  }
}

// ---------------- pass A #k via M^T: tacc_j += sum_i e_ij*u_i ----------------
// passB-shaped (R17-proven fast): uint4 loads, uv[16]/lane, scalar-per-row acc,
// shuffle reduce, 1 atomic/row. grid (8,128); 16 MT-rows (j) per wave.
__global__ __launch_bounds__(256,4) void k_passA(const unsigned char* __restrict__ Mt,
      const float* __restrict__ saccPrev, float* __restrict__ tacc,
      float* scal, int k){
  int tid=threadIdx.x, wave=tid>>6, lane=tid&63;
  int ibase = blockIdx.x*1024, rowbase = blockIdx.y*64 + wave*16;   // MT rows = j
  float c2 = scal[S_C2], Ks = scal[S_KS];
  float cs = c2*QSTEP, cb = c2*QLO;
  float Wp, wsp, Up, usp; chain(scal, Ks, k, Wp, wsp, Up, usp);
  float uv[16];
  if (k==1){
    #pragma unroll
    for (int b=0;b<16;b++) uv[b] = AB;
  } else {
    float addp = 1e-6f*Wp + Ks*wsp;
    const float* sp = saccPrev + ibase + lane*16;
    #pragma unroll
    for (int d4=0; d4<4; d4++){
      float4 s4 = *reinterpret_cast<const float4*>(sp + d4*4);
      uv[d4*4+0]=AB/(s4.x+addp); uv[d4*4+1]=AB/(s4.y+addp);
      uv[d4*4+2]=AB/(s4.z+addp); uv[d4*4+3]=AB/(s4.w+addp);
    }
  }
  if (blockIdx.y==0 && wave==0){       // uv depends only on (bx,lane): 8 bx cover all i once
    float t = 0.f;
    #pragma unroll
    for (int b=0;b<16;b++) t += uv[b];
    #pragma unroll
    for (int off=1; off<64; off<<=1) t += __shfl_xor(t, off);
    if (lane==0) atomicAdd(&scal[S_U(k-1)], t);
  }
  const unsigned char* mp = Mt + (size_t)rowbase*NCC + ibase + lane*16;
  for (int r0=0; r0<16; r0+=8){
    uint4 mv[8];
    #pragma unroll
    for (int q=0;q<8;q++) mv[q] = *reinterpret_cast<const uint4*>(mp + (size_t)(r0+q)*NCC);
    #pragma unroll
    for (int q=0;q<8;q++){
      float f[16]; cvt16(mv[q], f);
      float d = 0.f;
      #pragma unroll
      for (int b=0;b<16;b++)
        d = fmaf(EXP2R(fmaf(f[b], cs, cb)), uv[b], d);
      #pragma unroll
      for (int off=1; off<64; off<<=1) d += __shfl_xor(d, off);
      if (lane==0) atomicAdd(&tacc[rowbase + r0 + q], d);
    }
  }
}

// ---------------- pass B #k via M: sacc_i += sum_j e_ij*w_j (R17-proven, ~9.5us) ----------------
__global__ __launch_bounds__(256,4) void k_passB(const unsigned char* __restrict__ Mq,
      const float* __restrict__ tacc, float* __restrict__ sacc,
      float* scal, int k){
  int tid=threadIdx.x, wave=tid>>6, lane=tid&63;
  int jbase = blockIdx.x*1024, rowbase = blockIdx.y*64 + wave*16;
  float c2 = scal[S_C2], Ks = scal[S_KS];
  float cs = c2*QSTEP, cb = c2*QLO;
  float Wp, wsp, Up, usp; chain(scal, Ks, k, Wp, wsp, Up, usp);
  float addc = 1e-6f*Up + Ks*usp;
  const float* tp = tacc + jbase + lane*16;
  float wv[16];
  #pragma unroll
  for (int d4=0; d4<4; d4++){
    float4 t4 = *reinterpret_cast<const float4*>(tp + d4*4);
    wv[d4*4+0] = AB/(t4.x+addc); wv[d4*4+1] = AB/(t4.y+addc);
    wv[d4*4+2] = AB/(t4.z+addc); wv[d4*4+3] = AB/(t4.w+addc);
  }
  if (blockIdx.y==0 && wave==0){
    float s = 0.f;
    #pragma unroll
    for (int c=0;c<16;c++) s += wv[c];
    #pragma unroll
    for (int off=1; off<64; off<<=1) s += __shfl_xor(s, off);
    if (lane==0) atomicAdd(&scal[S_W(k)], s);
  }
  const unsigned char* mp = Mq + (size_t)rowbase*NCC + jbase + lane*16;
  for (int r0=0; r0<16; r0+=8){
    uint4 mv[8];
    #pragma unroll
    for (int q=0;q<8;q++) mv[q] = *reinterpret_cast<const uint4*>(mp + (size_t)(r0+q)*NCC);
    #pragma unroll
    for (int q=0;q<8;q++){
      float f[16]; cvt16(mv[q], f);
      float d = 0.f;
      #pragma unroll
      for (int b=0;b<16;b++)
        d = fmaf(EXP2R(fmaf(f[b], cs, cb)), wv[b], d);
      #pragma unroll
      for (int off=1; off<64; off<<=1) d += __shfl_xor(d, off);
      if (lane==0) atomicAdd(&sacc[rowbase + r0 + q], d);
    }
  }
}

// ---------------- pass 21 (A#11 + E prep) via M^T: tacc11_j, qa_j=sum u*e*m, pa_j=sum u*m ----------------
__global__ __launch_bounds__(256,4) void k_passAE(const unsigned char* __restrict__ Mt,
      const float* __restrict__ saccPrev, float* __restrict__ tacc,
      float* __restrict__ qa, float* __restrict__ pa, float* scal){
  const int k = 11;
  int tid=threadIdx.x, wave=tid>>6, lane=tid&63;
  int ibase = blockIdx.x*1024, rowbase = blockIdx.y*64 + wave*16;
  float c2 = scal[S_C2], Ks = scal[S_KS];
  float cs = c2*QSTEP, cb = c2*QLO;
  float Wp, wsp, Up, usp; chain(scal, Ks, k, Wp, wsp, Up, usp);
  float uv[16];
  {
    float addp = 1e-6f*Wp + Ks*wsp;
    const float* sp = saccPrev + ibase + lane*16;
    #pragma unroll
    for (int d4=0; d4<4; d4++){
      float4 s4 = *reinterpret_cast<const float4*>(sp + d4*4);
      uv[d4*4+0]=AB/(s4.x+addp); uv[d4*4+1]=AB/(s4.y+addp);
      uv[d4*4+2]=AB/(s4.z+addp); uv[d4*4+3]=AB/(s4.w+addp);
    }
  }
  if (blockIdx.y==0 && wave==0){
    float t = 0.f;
    #pragma unroll
    for (int b=0;b<16;b++) t += uv[b];
    #pragma unroll
    for (int off=1; off<64; off<<=1) t += __shfl_xor(t, off);
    if (lane==0) atomicAdd(&scal[S_U(10)], t);
  }
  const unsigned char* mp = Mt + (size_t)rowbase*NCC + ibase + lane*16;
  for (int r0=0; r0<16; r0+=8){
    uint4 mv[8];
    #pragma unroll
    for (int q=0;q<8;q++) mv[q] = *reinterpret_cast<const uint4*>(mp + (size_t)(r0+q)*NCC);
    #pragma unroll
    for (int q=0;q<8;q++){
      float f[16]; cvt16(mv[q], f);
      float dt = 0.f, dq = 0.f, dp = 0.f;
      #pragma unroll
      for (int b=0;b<16;b++){
        float m = fmaf(f[b], QSTEP, QLO);
        float e = EXP2R(fmaf(f[b], cs, cb));
        float eu = e * uv[b];
        dt += eu;
        dq = fmaf(eu, m, dq);
        dp = fmaf(uv[b], m, dp);
      }
      #pragma unroll
      for (int off=1; off<64; off<<=1){
        dt += __shfl_xor(dt, off);
        dq += __shfl_xor(dq, off);
        dp += __shfl_xor(dp, off);
      }
      if (lane==0){
        int j = rowbase + r0 + q;
        atomicAdd(&tacc[j], dt);
        atomicAdd(&qa[j], dq);
        atomicAdd(&pa[j], dp);
      }
    }
  }
}

// ---------------- final: v_j from t^11, E = sum v*(q+1e-6*p), slack terms, output ----------------
__global__ __launch_bounds__(256) void k_out(const float* __restrict__ tacc11,
      const float* __restrict__ qa, const float* __restrict__ pa,
      const float* scal, float* __restrict__ out){
  int tid=threadIdx.x, wave=tid>>6, lane=tid&63;
  float Ks = scal[S_KS], delta = scal[S_DELTA];
  float Wp, wsp, Up, usp; chain(scal, Ks, 11, Wp, wsp, Up, usp);
  float addc = 1e-6f*Up + Ks*usp;
  float Epart = 0.f, Vpart = 0.f;
  for (int j=tid; j<NCC; j+=256){
    float vj = AB/(tacc11[j] + addc);
    Vpart += vj;
    Epart = fmaf(vj, qa[j] + 1e-6f*pa[j], Epart);
  }
  #pragma unroll
  for (int off=1; off<64; off<<=1){
    Epart += __shfl_xor(Epart, off);
    Vpart += __shfl_xor(Vpart, off);
  }
  __shared__ float er[4], vr[4];
  if (lane==0){ er[wave]=Epart; vr[wave]=Vpart; }
  __syncthreads();
  if (tid==0){
    float E = er[0]+er[1]+er[2]+er[3];
    float V = vr[0]+vr[1]+vr[2]+vr[3];
    float vs = 0.5f/(Ks*Up + 1.000001f*usp);
    out[0] = 2.f*(E + delta*Ks*(usp*V + vs*Up));
  }
}

// ---------------- launch ----------------
extern "C" void kernel_launch(void* const* d_in, const int* in_sizes, int n_in,
                              void* d_out, int out_size, void* d_ws, size_t ws_size,
                              hipStream_t stream){
  (void)in_sizes; (void)n_in; (void)out_size; (void)ws_size;
  const float* X = (const float*)d_in[0];
  char* ws = (char*)d_ws;
  float*         scal = (float*)(ws + OFF_SCAL);
  float*         accs = (float*)(ws + OFF_ACC);
  float*         gp   = accs + (size_t)21*NCC;   // slabs 21..24
  float*         qa   = accs + (size_t)25*NCC;   // slab 25
  float*         pa   = accs + (size_t)26*NCC;   // slab 26
  float*         rn   = (float*)(ws + OFF_RN);
  short*         Xh   = (short*)(ws + OFF_XH);
  short*         Xl   = (short*)(ws + OFF_XL);
  unsigned char* Mq   = (unsigned char*)(ws + OFF_M);
  unsigned char* Mt   = (unsigned char*)(ws + OFF_MT);
  float*         out  = (float*)d_out;

  hipMemsetAsync(ws, 0, OFF_ACC + N_SLABS*NCC*4, stream);

  k_pack<<<NTOT/16, 256, 0, stream>>>(X, Xh, Xl, rn);
  k_gemm<<<dim3(128,128), 256, 0, stream>>>(Xh, Xl, Mq, Mt, rn, gp);
  k_scal<<<1, 256, 0, stream>>>(gp, scal);

  for (int k=1; k<=10; ++k){
    k_passA<<<dim3(8,128), 256, 0, stream>>>(Mt, accs + (size_t)(10+k-1)*NCC, accs + (size_t)(k-1)*NCC, scal, k);
    k_passB<<<dim3(8,128), 256, 0, stream>>>(Mq, accs + (size_t)(k-1)*NCC,   accs + (size_t)(10+k)*NCC, scal, k);
  }
  k_passAE<<<dim3(8,128), 256, 0, stream>>>(Mt, accs + (size_t)20*NCC, accs + (size_t)10*NCC, qa, pa, scal);
  k_out<<<1, 256, 0, stream>>>(accs + (size_t)10*NCC, qa, pa, scal, out);
}